// Round 1
// baseline (1254.690 us; speedup 1.0000x reference)
//
#include <hip/hip_runtime.h>

#define KCW 1024   // num codewords
#define DIM 64     // embedding dim

// ---------------------------------------------------------------------------
// Pre-kernel: cnorm[k] = sum_d codebook[k][d]^2   (1024 floats into d_ws)
// ---------------------------------------------------------------------------
__global__ void __launch_bounds__(256) vq_cnorm_kernel(const float* __restrict__ cb,
                                                       float* __restrict__ cnorm) {
    int k = blockIdx.x * blockDim.x + threadIdx.x;
    if (k < KCW) {
        const float4* c4 = (const float4*)(cb + (size_t)k * DIM);
        float s0 = 0.f, s1 = 0.f, s2 = 0.f, s3 = 0.f;
#pragma unroll
        for (int j = 0; j < DIM / 4; j += 4) {
            float4 a = c4[j + 0];
            float4 b = c4[j + 1];
            float4 c = c4[j + 2];
            float4 d = c4[j + 3];
            s0 += a.x * a.x + a.y * a.y + a.z * a.z + a.w * a.w;
            s1 += b.x * b.x + b.y * b.y + b.z * b.z + b.w * b.w;
            s2 += c.x * c.x + c.y * c.y + c.z * c.z + c.w * c.w;
            s3 += d.x * d.x + d.y * d.y + d.z * d.z + d.w * d.w;
        }
        cnorm[k] = (s0 + s1) + (s2 + s3);
    }
}

// ---------------------------------------------------------------------------
// Main kernel: one thread per row.
//   score(k) = cnorm[k] - 2 * dot(x_row, cb[k])   (argmin same as ref distance)
// Epilogue: block-cooperative coalesced writes of one-hot + quantized.
// ---------------------------------------------------------------------------
__global__ void __launch_bounds__(256) vq_main_kernel(const float* __restrict__ x,
                                                      const float* __restrict__ cb,
                                                      const float* __restrict__ cnorm,
                                                      float* __restrict__ out_discrete,
                                                      float* __restrict__ out_quant) {
    const int tid = threadIdx.x;
    const int row = blockIdx.x * 256 + tid;

    // Load this thread's x row into registers (16 x float4 = 64 VGPRs).
    float4 xv[16];
    {
        const float4* xr = (const float4*)(x + (size_t)row * DIM);
#pragma unroll
        for (int j = 0; j < 16; ++j) xv[j] = xr[j];
    }

    float best = 3.4e38f;
    int bestIdx = 0;

    // k is block-uniform -> codebook/cnorm loads should scalarize (s_load).
    for (int k = 0; k < KCW; ++k) {
        const float4* c4 = (const float4*)cb + (k << 4);
        float a0 = 0.f, a1 = 0.f, a2 = 0.f, a3 = 0.f;
#pragma unroll
        for (int j = 0; j < 16; j += 4) {
            float4 ca = c4[j + 0];
            float4 cbv = c4[j + 1];
            float4 cc = c4[j + 2];
            float4 cd = c4[j + 3];
            float4 xa = xv[j + 0];
            float4 xb = xv[j + 1];
            float4 xc = xv[j + 2];
            float4 xd = xv[j + 3];
            a0 = fmaf(xa.x, ca.x, a0);
            a0 = fmaf(xa.y, ca.y, a0);
            a0 = fmaf(xa.z, ca.z, a0);
            a0 = fmaf(xa.w, ca.w, a0);
            a1 = fmaf(xb.x, cbv.x, a1);
            a1 = fmaf(xb.y, cbv.y, a1);
            a1 = fmaf(xb.z, cbv.z, a1);
            a1 = fmaf(xb.w, cbv.w, a1);
            a2 = fmaf(xc.x, cc.x, a2);
            a2 = fmaf(xc.y, cc.y, a2);
            a2 = fmaf(xc.z, cc.z, a2);
            a2 = fmaf(xc.w, cc.w, a2);
            a3 = fmaf(xd.x, cd.x, a3);
            a3 = fmaf(xd.y, cd.y, a3);
            a3 = fmaf(xd.z, cd.z, a3);
            a3 = fmaf(xd.w, cd.w, a3);
        }
        float dot = (a0 + a1) + (a2 + a3);
        float score = fmaf(-2.f, dot, cnorm[k]);
        // strict < keeps the earliest index on ties, matching np.argmin
        if (score < best) {
            best = score;
            bestIdx = k;
        }
    }

    __shared__ int sIdx[256];
    sIdx[tid] = bestIdx;
    __syncthreads();

    // ---- quantized: rows [blockIdx*256, +256), 256*16 float4, coalesced ----
    {
        float4* q4 = (float4*)(out_quant + (size_t)blockIdx.x * 256 * DIM);
#pragma unroll
        for (int i = 0; i < 16; ++i) {
            int chunk = i * 256 + tid;
            int rl = chunk >> 4;   // local row (16 float4 per row)
            int j = chunk & 15;    // float4 index within row
            int idx = sIdx[rl];
            const float4* src = (const float4*)cb + (idx << 4);
            q4[chunk] = src[j];
        }
    }

    // ---- one-hot: 256 rows x 1024 floats, fully coalesced float4 stores ----
    {
        float4* o4 = (float4*)(out_discrete + (size_t)blockIdx.x * 256 * KCW);
        const int col = tid * 4;
        for (int it = 0; it < 256; ++it) {
            int idx = sIdx[it];  // block-uniform per iteration
            float4 v;
            v.x = (col + 0 == idx) ? 1.f : 0.f;
            v.y = (col + 1 == idx) ? 1.f : 0.f;
            v.z = (col + 2 == idx) ? 1.f : 0.f;
            v.w = (col + 3 == idx) ? 1.f : 0.f;
            o4[(size_t)it * 256 + tid] = v;
        }
    }
}

// ---------------------------------------------------------------------------
extern "C" void kernel_launch(void* const* d_in, const int* in_sizes, int n_in,
                              void* d_out, int out_size, void* d_ws, size_t ws_size,
                              hipStream_t stream) {
    const float* x = (const float*)d_in[0];
    const float* cb = (const float*)d_in[1];
    float* cnorm = (float*)d_ws;  // 1024 floats of scratch

    const int n = in_sizes[0];        // 8388608
    const int rows = n / DIM;         // 131072

    float* out_discrete = (float*)d_out;
    float* out_quant = (float*)d_out + (size_t)rows * KCW;

    vq_cnorm_kernel<<<(KCW + 255) / 256, 256, 0, stream>>>(cb, cnorm);
    vq_main_kernel<<<rows / 256, 256, 0, stream>>>(x, cb, cnorm, out_discrete, out_quant);
}